// Round 1
// baseline (276.604 us; speedup 1.0000x reference)
//
#include <hip/hip_runtime.h>

// SplineCNN on MI355X.
// Sparse edge extraction (adj ~6% dense, basis shared across layers);
// per-layer: split-bf16 MFMA GEMM [B*N,3K]x[3K,640] -> sparse aggregate
// (+root+bias+relu, emits next layer's split-bf16 input).
// Split-bf16: v = hi + lo (bf16 each); A slabs [hi|lo|hi], W slabs [hi;hi;lo]
// -> C = Ahi*Whi + Alo*Whi + Ahi*Wlo (drop lo*lo, ~5e-4 abs err).
// GEMM epilogue splits output: 9 tap slabs -> fp16 [M,576] (halves gather
// bytes, makes per-XCD working set L2-resident); root slab -> fp32 [M,64].
// Aggregate: XCD-swizzled grid (L2 locality), LDS-staged edge lists, x4 unroll,
// fp16 tap gathers (4x 128B/wave coalesced loads, single addr + imm offsets).
// Layer-2 aggregate fuses global max-pool via uint-bitcast atomicMax (relu >= 0).

#define B_   32
#define N_   512
#define F_   64
#define CAP  128          // max neighbors per node (mean ~31, 128 is >>6 sigma)
#define NCOL 640          // 9*F (spline kernels) + F (root)
#define TCOL 576          // 9*F tap columns kept in fp16 gather buffer

typedef short bf16x8 __attribute__((ext_vector_type(8)));
typedef float f32x4  __attribute__((ext_vector_type(4)));

__device__ __forceinline__ unsigned short to_bf16_rne(float v) {
  unsigned u = __float_as_uint(v);
  unsigned r = u + 0x7fffu + ((u >> 16) & 1u);
  return (unsigned short)(r >> 16);
}
__device__ __forceinline__ float bf16_to_f(unsigned short h) {
  return __uint_as_float(((unsigned)h) << 16);
}

// ---------------- preprocess: edge lists + factored spline basis ----------------
// edge record: float4 { bitcast(m | k0<<16), fx, fy, 1.0 } (w=1 marks valid; zero
// records give all-zero tap weights)
__global__ __launch_bounds__(512) void preprocess_kernel(
    const float* __restrict__ adj, const float* __restrict__ coord,
    float4* __restrict__ edge, int* __restrict__ cnt_out,
    float* __restrict__ deginv_out) {
  int row = blockIdx.x;          // b*N + n
  int b = row >> 9;
  int tid = threadIdx.x;         // == m
  int lane = tid & 63, wave = tid >> 6;
  __shared__ int wcnt[8];
  float a = adj[(size_t)row * N_ + tid];
  bool flag = (a != 0.0f);
  unsigned long long ball = __ballot(flag);
  if (lane == 0) wcnt[wave] = __popcll(ball);
  __syncthreads();
  int woff = 0, total = 0;
  #pragma unroll
  for (int i = 0; i < 8; ++i) { int c = wcnt[i]; if (i < wave) woff += c; total += c; }
  if (flag) {
    int pos = woff + __popcll(ball & ((1ULL << lane) - 1));
    if (pos < CAP) {
      int m = tid;
      float cxn = coord[(size_t)row * 2 + 0];
      float cyn = coord[(size_t)row * 2 + 1];
      float cxm = coord[(size_t)(b * N_ + m) * 2 + 0];
      float cym = coord[(size_t)(b * N_ + m) * 2 + 1];
      float vx = (cxm - cxn + 1.0f) * 0.5f * 2.0f;
      float vy = (cym - cyn + 1.0f) * 0.5f * 2.0f;
      float i0x = fminf(fmaxf(floorf(vx), 0.0f), 1.0f);
      float i0y = fminf(fmaxf(floorf(vy), 0.0f), 1.0f);
      float fx = vx - i0x, fy = vy - i0y;
      int k0c = (int)i0x * 3 + (int)i0y;
      edge[(size_t)row * CAP + pos] =
          make_float4(__int_as_float(m | (k0c << 16)), fx, fy, 1.0f);
    }
  }
  if (tid == 0) {
    cnt_out[row] = total > CAP ? CAP : total;
    deginv_out[row] = 1.0f / (float)(total > 0 ? total : 1);
  }
}

// ---------------- convert x (fp32 [M,128]) -> split-bf16 A [M, 384] ----------------
__global__ void convx_kernel(const float* __restrict__ x, unsigned short* __restrict__ a) {
  int idx = blockIdx.x * blockDim.x + threadIdx.x;
  if (idx >= B_ * N_ * 128) return;
  int row = idx >> 7, k = idx & 127;
  float v = x[idx];
  unsigned short hi = to_bf16_rne(v);
  unsigned short lo = to_bf16_rne(v - bf16_to_f(hi));
  size_t base = (size_t)row * 384;
  a[base + k] = hi;
  a[base + 128 + k] = lo;
  a[base + 256 + k] = hi;
}

// ---- pack w (9 slices)+root -> W^T split-bf16 [640 n][3*cin k'] (slabs hi,hi,lo) ----
__global__ void packw_kernel(const float* __restrict__ w, const float* __restrict__ root,
                             int cin, unsigned short* __restrict__ wt) {
  int idx = blockIdx.x * blockDim.x + threadIdx.x;
  int total = NCOL * cin;
  if (idx >= total) return;
  int n = idx / cin, k = idx - n * cin;
  int kk = n >> 6, f = n & 63;
  float v = (kk < 9) ? w[((size_t)kk * cin + k) * F_ + f]
                     : root[(size_t)k * F_ + f];
  unsigned short hi = to_bf16_rne(v);
  unsigned short lo = to_bf16_rne(v - bf16_to_f(hi));
  size_t base = (size_t)n * (3 * cin);
  wt[base + k] = hi;
  wt[base + cin + k] = hi;
  wt[base + 2 * cin + k] = lo;
}

// ---------------- split-bf16 MFMA GEMM: [M,640] = A[M,KP] * Wt[640,KP]^T ----------------
// 128x128 tile, 256 threads = 4 waves (2x2 of 64x64), 16x16x32 bf16 MFMA, BK=64.
// LDS rows padded +8 bf16 (stride 144B = 9 words -> conflict-free b128 frag reads).
// Epilogue: cols 0..575 (tap slabs) -> fp16 hwh; cols 576..639 (root) -> fp32 rootf.
// The 576 split is wave-uniform (n-tile 512..639 splits at wave nw boundary).
#define BK 64
#define LDK (BK + 8)
__global__ __launch_bounds__(256) void gemm_mfma_kernel(
    const unsigned short* __restrict__ A,   // [M][KP]
    const unsigned short* __restrict__ Wt,  // [640][KP]  (W^T, n-major)
    _Float16* __restrict__ hwh,             // [M][576] fp16 tap slabs
    float* __restrict__ rootf,              // [M][64] fp32 root slab
    int KP) {
  __shared__ unsigned short As[128 * LDK];
  __shared__ unsigned short Ws[128 * LDK];
  int bm = blockIdx.x * 128;
  int bn = blockIdx.y * 128;
  int tid = threadIdx.x;
  int wave = tid >> 6, lane = tid & 63;
  int mw = (wave & 1) * 64, nw = (wave >> 1) * 64;
  int lr = lane & 15, quad = lane >> 4;

  f32x4 acc[4][4] = {};
  for (int k0 = 0; k0 < KP; k0 += BK) {
    #pragma unroll
    for (int i = 0; i < 4; ++i) {
      int c = tid + i * 256;            // 0..1023 chunks of 16B
      int row = c >> 3, ck = (c & 7) * 8;
      *(float4*)&As[row * LDK + ck] =
          *(const float4*)&A[(size_t)(bm + row) * KP + k0 + ck];
      *(float4*)&Ws[row * LDK + ck] =
          *(const float4*)&Wt[(size_t)(bn + row) * KP + k0 + ck];
    }
    __syncthreads();
    #pragma unroll
    for (int kk = 0; kk < BK; kk += 32) {
      bf16x8 af[4], bf[4];
      #pragma unroll
      for (int i = 0; i < 4; ++i)
        af[i] = *(const bf16x8*)&As[(mw + 16 * i + lr) * LDK + kk + quad * 8];
      #pragma unroll
      for (int j = 0; j < 4; ++j)
        bf[j] = *(const bf16x8*)&Ws[(nw + 16 * j + lr) * LDK + kk + quad * 8];
      #pragma unroll
      for (int i = 0; i < 4; ++i)
        #pragma unroll
        for (int j = 0; j < 4; ++j)
          acc[i][j] = __builtin_amdgcn_mfma_f32_16x16x32_bf16(af[i], bf[j], acc[i][j], 0, 0, 0);
    }
    __syncthreads();
  }
  // epilogue: C/D layout col=lane&15, row=quad*4+reg (m89-verified)
  #pragma unroll
  for (int i = 0; i < 4; ++i)
    #pragma unroll
    for (int j = 0; j < 4; ++j)
      #pragma unroll
      for (int r = 0; r < 4; ++r) {
        int m = bm + mw + 16 * i + quad * 4 + r;
        int n = bn + nw + 16 * j + lr;
        float v = acc[i][j][r];
        if (n < TCOL)
          hwh[(size_t)m * TCOL + n] = (_Float16)v;
        else
          rootf[(size_t)m * F_ + (n - TCOL)] = v;
      }
}

// ---------------- sparse aggregate ----------------
// 256 threads = 4 waves, one row per wave. XCD-swizzled (blockIdx&7 = XCD).
// Edge lists staged to LDS, padded to x4 with zero records; x4 unrolled gathers.
// Taps gathered from fp16 hwh (one addr calc per edge + imm offsets; 128B/wave
// coalesced). Per-XCD resident set ~3.1 MB < 4 MiB L2.
// Emits next layer's split-bf16 A (aout: [row][192] = hi|lo|hi) and/or gmax.
__global__ __launch_bounds__(256) void aggregate_kernel(
    const _Float16* __restrict__ hwh,
    const float* __restrict__ rootf,
    const float4* __restrict__ edge,
    const int* __restrict__ cnt, const float* __restrict__ deginv,
    const float* __restrict__ bias,
    unsigned short* __restrict__ aout,
    unsigned int* __restrict__ gmax) {
  __shared__ float4 esh[4][CAP];
  int wave = threadIdx.x >> 6;
  int lane = threadIdx.x & 63;
  int f = lane;
  int xcd = blockIdx.x & 7;
  int j = blockIdx.x >> 3;
  int b = xcd * 4 + (j >> 7);
  int row = b * N_ + ((j & 127) << 2) + wave;
  int c = cnt[row];
  int cpad = (c + 3) & ~3;
  size_t ebase = (size_t)row * CAP;
  for (int i = lane; i < cpad; i += 64)
    esh[wave][i] = (i < c) ? edge[ebase + i] : make_float4(0.f, 0.f, 0.f, 0.f);
  __syncthreads();

  float di = deginv[row];
  const _Float16* hwb = hwh + (size_t)b * N_ * TCOL;
  float acc0 = 0.f, acc1 = 0.f, acc2 = 0.f, acc3 = 0.f;
  for (int e0 = 0; e0 < cpad; e0 += 4) {
    int off[4];
    float w00[4], w01[4], w10[4], w11[4];
    #pragma unroll
    for (int q = 0; q < 4; ++q) {
      float4 er = esh[wave][e0 + q];
      int mk = __float_as_int(er.x);
      off[q] = (mk & 0xffff) * TCOL + (mk >> 16) * F_ + f;
      float bx1 = er.y, by1 = er.z, v = er.w;
      float bx0 = v - bx1, by0 = v - by1;
      w00[q] = bx0 * by0; w01[q] = bx0 * by1;
      w10[q] = bx1 * by0; w11[q] = bx1 * by1;
    }
    float t0[4], t1[4], t2[4], t3[4];
    #pragma unroll
    for (int q = 0; q < 4; ++q) {
      const _Float16* p = hwb + off[q];
      t0[q] = (float)p[0];
      t1[q] = (float)p[F_];
      t2[q] = (float)p[3 * F_];
      t3[q] = (float)p[4 * F_];
    }
    acc0 += w00[0] * t0[0] + w01[0] * t1[0] + w10[0] * t2[0] + w11[0] * t3[0];
    acc1 += w00[1] * t0[1] + w01[1] * t1[1] + w10[1] * t2[1] + w11[1] * t3[1];
    acc2 += w00[2] * t0[2] + w01[2] * t1[2] + w10[2] * t2[2] + w11[2] * t3[2];
    acc3 += w00[3] * t0[3] + w01[3] * t1[3] + w10[3] * t2[3] + w11[3] * t3[3];
  }
  float rootv = rootf[(size_t)row * F_ + f];
  float val = fmaxf(((acc0 + acc1) + (acc2 + acc3)) * di + rootv + bias[f], 0.0f);
  if (aout) {
    unsigned short hi = to_bf16_rne(val);
    unsigned short lo = to_bf16_rne(val - bf16_to_f(hi));
    size_t base = (size_t)row * 192;
    aout[base + f] = hi;
    aout[base + 64 + f] = lo;
    aout[base + 128 + f] = hi;
  }
  if (gmax) {
    // relu output >= 0 -> IEEE bits monotone under unsigned compare
    atomicMax(&gmax[b * F_ + f], __float_as_uint(val));
  }
}

// ---------------- zero the pooled-max buffer ----------------
__global__ void zerog_kernel(unsigned int* __restrict__ g) {
  int i = blockIdx.x * blockDim.x + threadIdx.x;
  if (i < B_ * F_) g[i] = 0u;
}

// ---------------- FC from pooled features ----------------
__global__ __launch_bounds__(64) void fc_kernel(
    const float* __restrict__ g, const float* __restrict__ fcw,
    const float* __restrict__ fcb, float* __restrict__ out) {
  int b = blockIdx.x;
  int f = threadIdx.x;
  __shared__ float gs[64];
  gs[f] = g[b * F_ + f];
  __syncthreads();
  if (f < 10) {
    float s = fcb[f];
    #pragma unroll
    for (int c = 0; c < 64; ++c) s += gs[c] * fcw[c * 10 + f];
    out[b * 10 + f] = s;
  }
}

extern "C" void kernel_launch(void* const* d_in, const int* in_sizes, int n_in,
                              void* d_out, int out_size, void* d_ws, size_t ws_size,
                              hipStream_t stream) {
  const float* x     = (const float*)d_in[0];
  const float* coord = (const float*)d_in[1];
  const float* adj   = (const float*)d_in[2];
  const float* w0    = (const float*)d_in[3];
  const float* root0 = (const float*)d_in[4];
  const float* b0    = (const float*)d_in[5];
  const float* w1    = (const float*)d_in[6];
  const float* root1 = (const float*)d_in[7];
  const float* b1    = (const float*)d_in[8];
  const float* w2    = (const float*)d_in[9];
  const float* root2 = (const float*)d_in[10];
  const float* b2    = (const float*)d_in[11];
  const float* fcw   = (const float*)d_in[12];
  const float* fcb   = (const float*)d_in[13];
  float* out = (float*)d_out;

  char* ws = (char*)d_ws;
  size_t off = 0;
  auto alloc = [&](size_t bytes) {
    void* p = ws + off;
    off = (off + bytes + 255) & ~(size_t)255;
    return p;
  };
  const int R = B_ * N_;  // 16384
  float4* edge    = (float4*)alloc((size_t)R * CAP * 16);
  int*    cnt     = (int*)   alloc((size_t)R * 4);
  float*  deginv  = (float*) alloc((size_t)R * 4);
  unsigned short* abf0 = (unsigned short*)alloc((size_t)R * 384 * 2);
  unsigned short* abfN = (unsigned short*)alloc((size_t)R * 192 * 2);
  unsigned short* wt   = (unsigned short*)alloc((size_t)NCOL * 384 * 2);
  _Float16* hwh   = (_Float16*)alloc((size_t)R * TCOL * 2);
  float*  rootf   = (float*) alloc((size_t)R * F_ * 4);
  unsigned int* gmax = (unsigned int*)alloc((size_t)B_ * F_ * 4);

  preprocess_kernel<<<R, 512, 0, stream>>>(adj, coord, edge, cnt, deginv);
  zerog_kernel<<<(B_ * F_ + 255) / 256, 256, 0, stream>>>(gmax);
  convx_kernel<<<(R * 128 + 255) / 256, 256, 0, stream>>>(x, abf0);

  // layer 0 (Cin=128, KP=384)
  packw_kernel<<<(NCOL * 128 + 255) / 256, 256, 0, stream>>>(w0, root0, 128, wt);
  gemm_mfma_kernel<<<dim3(R / 128, NCOL / 128), 256, 0, stream>>>(abf0, wt, hwh, rootf, 384);
  aggregate_kernel<<<R / 4, 256, 0, stream>>>(hwh, rootf, edge, cnt, deginv, b0, abfN, nullptr);

  // layer 1 (Cin=64, KP=192)
  packw_kernel<<<(NCOL * 64 + 255) / 256, 256, 0, stream>>>(w1, root1, 64, wt);
  gemm_mfma_kernel<<<dim3(R / 128, NCOL / 128), 256, 0, stream>>>(abfN, wt, hwh, rootf, 192);
  aggregate_kernel<<<R / 4, 256, 0, stream>>>(hwh, rootf, edge, cnt, deginv, b1, abfN, nullptr);

  // layer 2 (Cin=64, KP=192) — fused max-pool
  packw_kernel<<<(NCOL * 64 + 255) / 256, 256, 0, stream>>>(w2, root2, 64, wt);
  gemm_mfma_kernel<<<dim3(R / 128, NCOL / 128), 256, 0, stream>>>(abfN, wt, hwh, rootf, 192);
  aggregate_kernel<<<R / 4, 256, 0, stream>>>(hwh, rootf, edge, cnt, deginv, b2, nullptr, gmax);

  fc_kernel<<<B_, 64, 0, stream>>>((const float*)gmax, fcw, fcb, out);
}